// Round 1
// baseline (31793.887 us; speedup 1.0000x reference)
//
#include <hip/hip_runtime.h>
#include <hip/hip_cooperative_groups.h>
#include <cmath>

namespace cg = cooperative_groups;

#define T_STEPS 1024
#define BATCH   128
#define IN_DIM  128
#define HID     256
#define OUT_DIM 128
#define KDEPTH  32

#define BT   16                 // batch rows per block
#define HT   16                 // h columns per block
#define NBT  (BATCH/BT)         // 8 batch tiles
#define NHG  (HID/HT)           // 16 h groups
#define NBLOCK (NBT*NHG)        // 128 blocks
#define NTHR 256

#define KTOT 384                // I + H (x part then h part)
#define S    388                // padded LDS row stride (floats), 388 % 32 == 4
#define SO   260                // padded stride for Wo rows

// LDS layout (float offsets)
#define OFF_WT   0                       // 48 cols (i|o|g per h) x S
#define OFF_WDT  (48*S)                  // 16 cols x S
#define OFF_WOT  (64*S)                  // 8 cols x SO
#define OFF_ACT  (64*S + 8*SO)           // 16 rows x S  (x_t || h_{t-1})
#define SMEM_FLOATS (64*S + 8*SO + 16*S)
#define SMEM_BYTES  (SMEM_FLOATS*4)

__device__ __forceinline__ float dot4(float4 a, float4 b, float acc) {
    acc = fmaf(a.x, b.x, acc);
    acc = fmaf(a.y, b.y, acc);
    acc = fmaf(a.z, b.z, acc);
    acc = fmaf(a.w, b.w, acc);
    return acc;
}

__device__ __forceinline__ float sigmoidf_(float x) {
    return 1.0f / (1.0f + expf(-x));
}

__global__ void __launch_bounds__(NTHR, 1)
mlstm_frac_kernel(const float* __restrict__ x,
                  const float* __restrict__ Wx,
                  const float* __restrict__ Wh,
                  const float* __restrict__ bvec,
                  const float* __restrict__ Wdx,
                  const float* __restrict__ Wdh,
                  const float* __restrict__ bd,
                  const float* __restrict__ Wo,
                  const float* __restrict__ bo,
                  float* __restrict__ out)
{
    extern __shared__ float sm[];
    cg::grid_group grid = cg::this_grid();

    const int tid = threadIdx.x;
    const int bt  = blockIdx.x & (NBT - 1);   // batch tile
    const int hg  = blockIdx.x >> 3;          // h group
    const int Bb  = bt * BT;
    const int Hb  = hg * HT;
    const int ob  = hg * 8;                   // this block's 8 y columns

    const int bl = tid >> 4;    // 0..15 local batch row
    const int hl = tid & 15;    // 0..15 local h col

    // ---- one-time: weights -> LDS, transposed + padded ----
    for (int idx = tid; idx < 48 * KTOT; idx += NTHR) {
        int k = idx / 48, c = idx % 48;
        int gcol = (c >> 4) * HID + Hb + (c & 15);   // i/o/g column in [0,768)
        float v = (k < IN_DIM) ? Wx[k * 768 + gcol]
                               : Wh[(k - IN_DIM) * 768 + gcol];
        sm[OFF_WT + c * S + k] = v;
    }
    for (int idx = tid; idx < 16 * KTOT; idx += NTHR) {
        int k = idx / 16, c = idx % 16;
        float v = (k < IN_DIM) ? Wdx[k * HID + Hb + c]
                               : Wdh[(k - IN_DIM) * HID + Hb + c];
        sm[OFF_WDT + c * S + k] = v;
    }
    for (int idx = tid; idx < 8 * HID; idx += NTHR) {
        int k = idx / 8, c = idx % 8;
        sm[OFF_WOT + c * SO + k] = Wo[k * OUT_DIM + ob + c];
    }

    const int hglob = Hb + hl;
    const float bi_r = bvec[hglob];
    const float bo_r = bvec[HID + hglob];
    const float bg_r = bvec[2 * HID + hglob];
    const float bd_r = bd[hglob];

    float hist[KDEPTH];
#pragma unroll
    for (int j = 0; j < KDEPTH; ++j) hist[j] = 0.0f;

    // d_out layout: y (T*B*O) | h_f (B*H) | hc_f (K*B*H) | d_f (B*H)
    float* ybase = out;
    float* hfin  = out + (size_t)T_STEPS * BATCH * OUT_DIM;
    float* hcf   = hfin + BATCH * HID;
    float* dfin  = hcf + (size_t)KDEPTH * BATCH * HID;

    // h ping-pong: buf0 borrows the hc_f region (not written until epilogue),
    // buf1 is the h_f region itself (so final h lands in place).
    float* hb0 = hcf;
    float* hb1 = hfin;

    float dlast = 0.0f;

    for (int t = 0; t < T_STEPS; ++t) {
        const float* hprev = (t & 1) ? hb0 : hb1;   // written at step t-1

        // ---- stage activations: act[b][0..127]=x_t, act[b][128..383]=h_{t-1}
        {
            const float* xt = x + (size_t)t * BATCH * IN_DIM;
            for (int idx = tid * 4; idx < BT * KTOT; idx += NTHR * 4) {
                int row = idx / KTOT, col = idx % KTOT;
                float4 v;
                if (col < IN_DIM)
                    v = *(const float4*)(xt + (size_t)(Bb + row) * IN_DIM + col);
                else if (t > 0)
                    v = *(const float4*)(hprev + (size_t)(Bb + row) * HID + (col - IN_DIM));
                else
                    v = make_float4(0.f, 0.f, 0.f, 0.f);
                *(float4*)(sm + OFF_ACT + row * S + col) = v;
            }
        }
        __syncthreads();

        // ---- phase 1: gate + d pre-activations for this thread's (b,h) ----
        float ai = bi_r, ao = bo_r, ag = bg_r, ad = bd_r;
        {
            const float4* ar = (const float4*)(sm + OFF_ACT + bl * S);
            const float4* wi = (const float4*)(sm + OFF_WT + hl * S);
            const float4* wo = (const float4*)(sm + OFF_WT + (16 + hl) * S);
            const float4* wg = (const float4*)(sm + OFF_WT + (32 + hl) * S);
            const float4* wd = (const float4*)(sm + OFF_WDT + hl * S);
#pragma unroll 4
            for (int kk = 0; kk < KTOT / 4; ++kk) {
                float4 a = ar[kk];
                ai = dot4(a, wi[kk], ai);
                ao = dot4(a, wo[kk], ao);
                ag = dot4(a, wg[kk], ag);
                ad = dot4(a, wd[kk], ad);
            }
        }

        // ---- deferred y_{t-1} = h_{t-1} @ Wo + bo (h part already in LDS) --
        if (t > 0 && tid < BT * 8) {
            int yb = tid >> 3, ol = tid & 7;
            float acc = bo[ob + ol];
            const float4* hr = (const float4*)(sm + OFF_ACT + yb * S + IN_DIM);
            const float4* wr = (const float4*)(sm + OFF_WOT + ol * SO);
#pragma unroll 4
            for (int kk = 0; kk < HID / 4; ++kk)
                acc = dot4(hr[kk], wr[kk], acc);
            ybase[((size_t)(t - 1) * BATCH + Bb + yb) * OUT_DIM + ob + ol] = acc;
        }

        // ---- phase 2: elementwise update with fractional memory filter ----
        float iv = sigmoidf_(ai);
        float ov = sigmoidf_(ao);
        float gv = tanhf(ag);
        float dv = 0.5f * sigmoidf_(ad);

        float w = dv;
        float facc = w * hist[0];
#pragma unroll
        for (int j = 2; j <= KDEPTH; ++j) {
            w *= ((float)(j - 1) - dv) * (1.0f / (float)j);
            facc = fmaf(w, hist[j - 1], facc);
        }
        float cnew = fmaf(iv, gv, facc);
        float hn = ov * tanhf(cnew);

#pragma unroll
        for (int j = KDEPTH - 1; j > 0; --j) hist[j] = hist[j - 1];
        hist[0] = cnew;
        dlast = dv;

        ((t & 1) ? hb1 : hb0)[(size_t)(Bb + bl) * HID + hglob] = hn;

        grid.sync();
    }

    // ---- epilogue: y_{T-1}, hc_f, d_f (h_f already in place = hb1) ----
    for (int idx = tid * 4; idx < BT * HID; idx += NTHR * 4) {
        int row = idx / HID, col = idx % HID;
        *(float4*)(sm + OFF_ACT + row * S + IN_DIM + col) =
            *(const float4*)(hb1 + (size_t)(Bb + row) * HID + col);
    }
    __syncthreads();

    if (tid < BT * 8) {
        int yb = tid >> 3, ol = tid & 7;
        float acc = bo[ob + ol];
        const float4* hr = (const float4*)(sm + OFF_ACT + yb * S + IN_DIM);
        const float4* wr = (const float4*)(sm + OFF_WOT + ol * SO);
#pragma unroll 4
        for (int kk = 0; kk < HID / 4; ++kk)
            acc = dot4(hr[kk], wr[kk], acc);
        ybase[((size_t)(T_STEPS - 1) * BATCH + Bb + yb) * OUT_DIM + ob + ol] = acc;
    }

#pragma unroll
    for (int j = 0; j < KDEPTH; ++j)
        hcf[((size_t)j * BATCH + Bb + bl) * HID + hglob] = hist[j];
    dfin[(size_t)(Bb + bl) * HID + hglob] = dlast;
}

extern "C" void kernel_launch(void* const* d_in, const int* in_sizes, int n_in,
                              void* d_out, int out_size, void* d_ws, size_t ws_size,
                              hipStream_t stream)
{
    const float* x   = (const float*)d_in[0];
    const float* Wx  = (const float*)d_in[1];
    const float* Wh  = (const float*)d_in[2];
    const float* b   = (const float*)d_in[3];
    const float* Wdx = (const float*)d_in[4];
    const float* Wdh = (const float*)d_in[5];
    const float* bd  = (const float*)d_in[6];
    const float* Wo  = (const float*)d_in[7];
    const float* bo  = (const float*)d_in[8];
    float* out = (float*)d_out;

    (void)d_ws; (void)ws_size; (void)in_sizes; (void)n_in; (void)out_size;

    static bool attr_set = false;
    // idempotent; safe to call every time (host-side attribute, not a stream op)
    hipFuncSetAttribute((const void*)mlstm_frac_kernel,
                        hipFuncAttributeMaxDynamicSharedMemorySize, SMEM_BYTES);
    (void)attr_set;

    void* args[] = { (void*)&x, (void*)&Wx, (void*)&Wh, (void*)&b,
                     (void*)&Wdx, (void*)&Wdh, (void*)&bd, (void*)&Wo,
                     (void*)&bo, (void*)&out };

    hipLaunchCooperativeKernel((const void*)mlstm_frac_kernel,
                               dim3(NBLOCK), dim3(NTHR),
                               args, SMEM_BYTES, stream);
}